// Round 12
// baseline (1278.798 us; speedup 1.0000x reference)
//
#include <hip/hip_runtime.h>

typedef _Float16 f16;
typedef _Float16 f16x4 __attribute__((ext_vector_type(4)));
typedef _Float16 f16x8 __attribute__((ext_vector_type(8)));
typedef float f32x2 __attribute__((ext_vector_type(2)));
typedef float f32x4 __attribute__((ext_vector_type(4)));

#define LSTM_B 256
#define LSTM_H 1024
#define LSTM_O 512
#define LSTM_T 128
#define GATES 4096

// hist blocked layout (r5-verified): element (t, b, h) at
//   ((t*64 + (h>>4))*4 + (b>>6))*1024 + (b&63)*16 + (h&15)
// -> each producer WG writes ONE contiguous 2KB block per step.

// ---------------- fp32 -> fp16 convert (vectorized) ----------------
__global__ void cvt4_kernel(const float4* __restrict__ src, f16x4* __restrict__ dst, int n4) {
  int i = blockIdx.x * blockDim.x + threadIdx.x;
  int st = gridDim.x * blockDim.x;
  for (; i < n4; i += st) {
    float4 v = src[i];
    f16x4 o; o[0] = (f16)v.x; o[1] = (f16)v.y; o[2] = (f16)v.z; o[3] = (f16)v.w;
    dst[i] = o;
  }
}

// ---------------- pack Whh into fragment-linear f16 layout (r5-verified) -------
__global__ void pack_whh_kernel(const float* __restrict__ Whh, f16* __restrict__ Wpack) {
  int idx = blockIdx.x * 256 + threadIdx.x;      // 64*128*64 = 524288 threads
  int lane = idx & 63;
  int f = (idx >> 6) & 127;
  int hj = idx >> 13;
  int kc = f >> 3, s = (f >> 2) & 1, wn = (f >> 1) & 1, nt = f & 1;
  int c = wn * 32 + nt * 16 + (lane & 15);
  int row = (c >> 4) * 1024 + hj * 16 + (c & 15);
  int k0 = kc * 64 + s * 32 + (lane >> 4) * 8;
  const float* src = Whh + (size_t)row * LSTM_H + k0;
  float4 v0 = *(const float4*)src;
  float4 v1 = *(const float4*)(src + 4);
  f16x8 o;
  o[0] = (f16)v0.x; o[1] = (f16)v0.y; o[2] = (f16)v0.z; o[3] = (f16)v0.w;
  o[4] = (f16)v1.x; o[5] = (f16)v1.y; o[6] = (f16)v1.z; o[7] = (f16)v1.w;
  *(f16x8*)(Wpack + (size_t)idx * 8) = o;
}

// ---------------- generic C[M,N] = A[MxK] * Bw[NxK]^T + bias ----------------
__global__ __launch_bounds__(256) void gemm_bt_kernel(
    const f16* __restrict__ A, const f16* __restrict__ Bw,
    const float* __restrict__ bias0, const float* __restrict__ bias1,
    float* __restrict__ out, int M, int N, int K, int gn, int xswz, int blkA)
{
  __shared__ __align__(16) f16 As[64][72];
  __shared__ __align__(16) f16 Bs[64][72];
  int bx = blockIdx.x;
  if (xswz) { int n = gridDim.x; bx = (bx & 7) * (n >> 3) + (bx >> 3); }  // bijective: n%8==0
  int mb = bx / gn;
  int m0 = mb * 64;
  int n0 = (bx - mb * gn) * 64;
  int tid = threadIdx.x;
  int lane = tid & 63, w = tid >> 6;
  int wm = w >> 1, wn = w & 1;
  int sr = tid >> 2, sseg = tid & 3;
  const f16* ga;
  size_t kadv;
  if (blkA) {
    int m = m0 + sr;
    ga = A + ((size_t)(m >> 8) * 256 + (size_t)sseg * 4 + ((m >> 6) & 3)) * 1024 + (m & 63) * 16;
    kadv = 16384;
  } else {
    ga = A + (size_t)(m0 + sr) * K + sseg * 16;
    kadv = 64;
  }
  const f16* gb = Bw + (size_t)(n0 + sr) * K + sseg * 16;
  f32x4 acc00 = {}, acc01 = {}, acc10 = {}, acc11 = {};
  f16x8 ra0 = *(const f16x8*)ga, ra1 = *(const f16x8*)(ga + 8);
  f16x8 rb0 = *(const f16x8*)gb, rb1 = *(const f16x8*)(gb + 8);
  for (int kc = 0; kc < K; kc += 64) {
    __syncthreads();
    *(f16x8*)&As[sr][sseg * 16]     = ra0;
    *(f16x8*)&As[sr][sseg * 16 + 8] = ra1;
    *(f16x8*)&Bs[sr][sseg * 16]     = rb0;
    *(f16x8*)&Bs[sr][sseg * 16 + 8] = rb1;
    __syncthreads();
    if (kc + 64 < K) {
      ga += kadv; gb += 64;
      ra0 = *(const f16x8*)ga; ra1 = *(const f16x8*)(ga + 8);
      rb0 = *(const f16x8*)gb; rb1 = *(const f16x8*)(gb + 8);
    }
    int g = lane >> 4, r = lane & 15;
    #pragma unroll
    for (int s = 0; s < 2; s++) {
      f16x8 a0 = *(const f16x8*)&As[wm * 32      + r][s * 32 + g * 8];
      f16x8 a1 = *(const f16x8*)&As[wm * 32 + 16 + r][s * 32 + g * 8];
      f16x8 b0 = *(const f16x8*)&Bs[wn * 32      + r][s * 32 + g * 8];
      f16x8 b1 = *(const f16x8*)&Bs[wn * 32 + 16 + r][s * 32 + g * 8];
      acc00 = __builtin_amdgcn_mfma_f32_16x16x32_f16(a0, b0, acc00, 0, 0, 0);
      acc01 = __builtin_amdgcn_mfma_f32_16x16x32_f16(a0, b1, acc01, 0, 0, 0);
      acc10 = __builtin_amdgcn_mfma_f32_16x16x32_f16(a1, b0, acc10, 0, 0, 0);
      acc11 = __builtin_amdgcn_mfma_f32_16x16x32_f16(a1, b1, acc11, 0, 0, 0);
    }
  }
  int gq = lane >> 4, rr = lane & 15;
  f32x4 accs[2][2] = {{acc00, acc01}, {acc10, acc11}};
  #pragma unroll
  for (int mt = 0; mt < 2; mt++)
    #pragma unroll
    for (int nt = 0; nt < 2; nt++) {
      int row = m0 + wm * 32 + mt * 16 + gq * 4;
      int col = n0 + wn * 32 + nt * 16 + rr;
      float bv = bias0 ? bias0[col] : 0.f;
      if (bias1) bv += bias1[col];
      #pragma unroll
      for (int j = 0; j < 4; j++)
        out[(size_t)(row + j) * N + col] = accs[mt][nt][j] + bv;
    }
}

// ---------------- persistent LSTM recurrence (r5 + BK=128 staging) -------------
// Identical to r5 except A staging processes TWO chunks per K-iteration from a
// 16KB buffer half (2x16KB double buffer): 8 __syncthreads in the K-loop
// instead of 16. Same wait_chunk, same prefetch lead, same epilogue/signaling.
__device__ __forceinline__ void wait_chunk(const unsigned* p) {
  while (__hip_atomic_load(p, __ATOMIC_RELAXED, __HIP_MEMORY_SCOPE_AGENT) < 4u)
    __builtin_amdgcn_s_sleep(2);
  asm volatile("" ::: "memory");   // block hoisting of A-loads above the flag
}

__global__ __launch_bounds__(256, 1) void lstm_persist_kernel(
    const f16* __restrict__ Wpack, const float* __restrict__ xp,
    f16* __restrict__ hist, unsigned* __restrict__ ready)
{
  __shared__ __align__(16) f16 Bres[65536];      // 128 KB resident Whh frags
  __shared__ __align__(16) char smx[32768];      // A dbuf 2x16KB / gsm overlay

  char* Ab = smx;
  float (*gsm)[65] = (float(*)[65])smx;          // overlays buf0 (+256B of buf1), dead post-K-loop

  const int wg = blockIdx.x;
  const int mb = (wg & 7) >> 1;                        // XCD pair -> batch group
  const int hj = ((wg >> 3) << 1) | (wg & 1);          // 64 hid-slices per group
  const int m0 = mb * 64;
  const int tid = threadIdx.x;
  const int lane = tid & 63, w = tid >> 6;
  const int wm = w >> 1, wn = w & 1;
  const int g = lane >> 4, r = lane & 15;

  // one-time: Whh fragment strip -> LDS
  {
    const f16x8* src = (const f16x8*)(Wpack + (size_t)hj * 65536);
    f16x8* dst = (f16x8*)Bres;
    for (int i = tid; i < 8192; i += 256) dst[i] = src[i];
  }

  // one-time: per-thread x_proj and c registers
  const int b_loc = tid & 63, hh0 = tid >> 6;
  const float* xprow = xp + (size_t)(m0 + b_loc) * GATES + hj * 16 + hh0 * 4;
  float4 xi = *(const float4*)(xprow);
  float4 xf = *(const float4*)(xprow + LSTM_H);
  float4 xg = *(const float4*)(xprow + 2 * LSTM_H);
  float4 xo = *(const float4*)(xprow + 3 * LSTM_H);
  float xiv[4] = {xi.x, xi.y, xi.z, xi.w};
  float xfv[4] = {xf.x, xf.y, xf.z, xf.w};
  float xgv[4] = {xg.x, xg.y, xg.z, xg.w};
  float xov[4] = {xo.x, xo.y, xo.z, xo.w};
  float cvv[4] = {0.f, 0.f, 0.f, 0.f};

  // staging geometry (r5-verified offsets; chunk slot = +c*8192 within a 16KB buf)
  const int sr = tid >> 2, sseg = tid & 3;
  const int wb0 = sr * 128 + ((sseg * 32)      ^ ((sr & 7) << 4));
  const int wb1 = sr * 128 + ((sseg * 32 + 16) ^ ((sr & 7) << 4));
  const int xr = (r & 7) << 4;
  const int rb00 = (wm * 32 + r) * 128 + ((g * 16)      ^ xr);
  const int rb01 = (wm * 32 + r) * 128 + ((64 + g * 16) ^ xr);
  const int rb10 = rb00 + 16 * 128;
  const int rb11 = rb01 + 16 * 128;
  const int bb = wn * 2048 + lane * 16;
  const int stag = hj >> 2;                            // own chunk first
  const f16* tb_base = hist + (size_t)sseg * 4096 + (size_t)mb * 1024 + sr * 16;
  f16* hob = hist + ((size_t)hj * 4 + mb) * 1024 + b_loc * 16 + hh0 * 4;

  __syncthreads();   // Bres ready

  for (int t = 0; t < LSTM_T; t++) {
    f32x4 acc00 = {}, acc01 = {}, acc10 = {}, acc11 = {};
    if (t > 0) {
      const f16* tb = tb_base + (size_t)(t - 1) * 262144;
      const unsigned* rdt = ready + (size_t)(t - 1) * 1024 + (size_t)mb * 256;
      // prologue: chunks stag,stag+1 -> buf0; chunks stag+2,stag+3 -> regs
      {
        const int k0 = stag;
        const int k1 = (stag + 1) & 15;
        wait_chunk(rdt + k0 * 16);
        f16x8 t0 = *(const f16x8*)(tb + (size_t)k0 * 16384);
        f16x8 t1 = *(const f16x8*)(tb + (size_t)k0 * 16384 + 8);
        wait_chunk(rdt + k1 * 16);
        f16x8 t2 = *(const f16x8*)(tb + (size_t)k1 * 16384);
        f16x8 t3 = *(const f16x8*)(tb + (size_t)k1 * 16384 + 8);
        *(f16x8*)(Ab + wb0)        = t0;
        *(f16x8*)(Ab + wb1)        = t1;
        *(f16x8*)(Ab + 8192 + wb0) = t2;
        *(f16x8*)(Ab + 8192 + wb1) = t3;
      }
      f16x8 ra0, ra1, ra2, ra3;
      {
        const int k2 = (stag + 2) & 15;
        const int k3 = (stag + 3) & 15;
        wait_chunk(rdt + k2 * 16);
        ra0 = *(const f16x8*)(tb + (size_t)k2 * 16384);
        ra1 = *(const f16x8*)(tb + (size_t)k2 * 16384 + 8);
        wait_chunk(rdt + k3 * 16);
        ra2 = *(const f16x8*)(tb + (size_t)k3 * 16384);
        ra3 = *(const f16x8*)(tb + (size_t)k3 * 16384 + 8);
      }
      __syncthreads();
      #pragma unroll 2
      for (int i = 0; i < 8; i++) {
        const int bo = (i & 1) * 16384;
        f16x8 rn0 = {}, rn1 = {}, rn2 = {}, rn3 = {};
        if (i < 6) {                                   // prefetch chunks 2i+4, 2i+5
          const int kl0 = (stag + 2 * i + 4) & 15;
          wait_chunk(rdt + kl0 * 16);
          rn0 = *(const f16x8*)(tb + (size_t)kl0 * 16384);
          rn1 = *(const f16x8*)(tb + (size_t)kl0 * 16384 + 8);
          const int kl1 = (stag + 2 * i + 5) & 15;
          wait_chunk(rdt + kl1 * 16);
          rn2 = *(const f16x8*)(tb + (size_t)kl1 * 16384);
          rn3 = *(const f16x8*)(tb + (size_t)kl1 * 16384 + 8);
        }
        // chunk 2i (slot 0 of buf)
        {
          const int kc = (stag + 2 * i) & 15;
          const char* Bb = (const char*)Bres + kc * 8192;
          const char* Asl = Ab + bo;
          f16x8 a00 = *(const f16x8*)(Asl + rb00);
          f16x8 a10 = *(const f16x8*)(Asl + rb10);
          f16x8 b00 = *(const f16x8*)(Bb + bb);
          f16x8 b10 = *(const f16x8*)(Bb + bb + 1024);
          acc00 = __builtin_amdgcn_mfma_f32_16x16x32_f16(a00, b00, acc00, 0, 0, 0);
          acc01 = __builtin_amdgcn_mfma_f32_16x16x32_f16(a00, b10, acc01, 0, 0, 0);
          acc10 = __builtin_amdgcn_mfma_f32_16x16x32_f16(a10, b00, acc10, 0, 0, 0);
          acc11 = __builtin_amdgcn_mfma_f32_16x16x32_f16(a10, b10, acc11, 0, 0, 0);
          f16x8 a01 = *(const f16x8*)(Asl + rb01);
          f16x8 a11 = *(const f16x8*)(Asl + rb11);
          f16x8 b01 = *(const f16x8*)(Bb + 4096 + bb);
          f16x8 b11 = *(const f16x8*)(Bb + 4096 + bb + 1024);
          acc00 = __builtin_amdgcn_mfma_f32_16x16x32_f16(a01, b01, acc00, 0, 0, 0);
          acc01 = __builtin_amdgcn_mfma_f32_16x16x32_f16(a01, b11, acc01, 0, 0, 0);
          acc10 = __builtin_amdgcn_mfma_f32_16x16x32_f16(a11, b01, acc10, 0, 0, 0);
          acc11 = __builtin_amdgcn_mfma_f32_16x16x32_f16(a11, b11, acc11, 0, 0, 0);
        }
        // chunk 2i+1 (slot 1 of buf)
        {
          const int kc = (stag + 2 * i + 1) & 15;
          const char* Bb = (const char*)Bres + kc * 8192;
          const char* Asl = Ab + bo + 8192;
          f16x8 a00 = *(const f16x8*)(Asl + rb00);
          f16x8 a10 = *(const f16x8*)(Asl + rb10);
          f16x8 b00 = *(const f16x8*)(Bb + bb);
          f16x8 b10 = *(const f16x8*)(Bb + bb + 1024);
          acc00 = __builtin_amdgcn_mfma_f32_16x16x32_f16(a00, b00, acc00, 0, 0, 0);
          acc01 = __builtin_amdgcn_mfma_f32_16x16x32_f16(a00, b10, acc01, 0, 0, 0);
          acc10 = __builtin_amdgcn_mfma_f32_16x16x32_f16(a10, b00, acc10, 0, 0, 0);
          acc11 = __builtin_amdgcn_mfma_f32_16x16x32_f16(a10, b10, acc11, 0, 0, 0);
          f16x8 a01 = *(const f16x8*)(Asl + rb01);
          f16x8 a11 = *(const f16x8*)(Asl + rb11);
          f16x8 b01 = *(const f16x8*)(Bb + 4096 + bb);
          f16x8 b11 = *(const f16x8*)(Bb + 4096 + bb + 1024);
          acc00 = __builtin_amdgcn_mfma_f32_16x16x32_f16(a01, b01, acc00, 0, 0, 0);
          acc01 = __builtin_amdgcn_mfma_f32_16x16x32_f16(a01, b11, acc01, 0, 0, 0);
          acc10 = __builtin_amdgcn_mfma_f32_16x16x32_f16(a11, b01, acc10, 0, 0, 0);
          acc11 = __builtin_amdgcn_mfma_f32_16x16x32_f16(a11, b11, acc11, 0, 0, 0);
        }
        if (i < 7) {                                   // stage chunks 2i+2, 2i+3
          char* dst = Ab + (bo ^ 16384);
          *(f16x8*)(dst + wb0)        = ra0;
          *(f16x8*)(dst + wb1)        = ra1;
          *(f16x8*)(dst + 8192 + wb0) = ra2;
          *(f16x8*)(dst + 8192 + wb1) = ra3;
          ra0 = rn0; ra1 = rn1; ra2 = rn2; ra3 = rn3;
        }
        __syncthreads();
      }
    }
    // gates tile -> gsm overlay
    {
      f32x4 accs[2][2] = {{acc00, acc01}, {acc10, acc11}};
      #pragma unroll
      for (int mt = 0; mt < 2; mt++)
        #pragma unroll
        for (int nt = 0; nt < 2; nt++)
          #pragma unroll
          for (int j = 0; j < 4; j++)
            gsm[wm * 32 + mt * 16 + g * 4 + j][wn * 32 + nt * 16 + r] = accs[mt][nt][j];
    }
    __syncthreads();
    // elementwise cell update (c and x_proj in registers)
    float hnew[4];
    #pragma unroll
    for (int u = 0; u < 4; u++) {
      int hh = hh0 * 4 + u;
      float iv = gsm[b_loc][hh]      + xiv[u];
      float fv = gsm[b_loc][16 + hh] + xfv[u];
      float gv = gsm[b_loc][32 + hh] + xgv[u];
      float ov = gsm[b_loc][48 + hh] + xov[u];
      iv = 1.f / (1.f + __expf(-iv));
      fv = 1.f / (1.f + __expf(-fv));
      gv = 2.f / (1.f + __expf(-2.f * gv)) - 1.f;
      ov = 1.f / (1.f + __expf(-ov));
      float cn = fv * cvv[u] + iv * gv;
      cvv[u] = cn;
      float tc = 2.f / (1.f + __expf(-2.f * cn)) - 1.f;
      hnew[u] = ov * tc;
    }
    f16x4 hw; hw[0] = (f16)hnew[0]; hw[1] = (f16)hnew[1]; hw[2] = (f16)hnew[2]; hw[3] = (f16)hnew[3];
    // write-through store (sc0 sc1): coherent at LLC, no dirty L2 line
    {
      union { f16x4 h; f32x2 f2; } hu; hu.h = hw;
      f16* haddr = hob + (size_t)t * 262144;
      asm volatile("global_store_dwordx2 %0, %1, off sc0 sc1" :: "v"(haddr), "v"(hu.f2) : "memory");
    }
    asm volatile("s_waitcnt vmcnt(0)" ::: "memory");   // this wave's h-store at LLC
    __syncthreads();                                   // all waves drained (+ gsm reads done)
    if (tid == 0 && t + 1 < LSTM_T)
      __hip_atomic_fetch_add(ready + (size_t)t * 1024 + (size_t)mb * 256 + (size_t)(hj >> 2) * 16,
                             1u, __ATOMIC_RELAXED, __HIP_MEMORY_SCOPE_AGENT);
  }
}

extern "C" void kernel_launch(void* const* d_in, const int* in_sizes, int n_in,
                              void* d_out, int out_size, void* d_ws, size_t ws_size,
                              hipStream_t stream)
{
  (void)in_sizes; (void)n_in; (void)out_size; (void)ws_size;
  const float* C     = (const float*)d_in[0];
  const float* W_ih  = (const float*)d_in[1];
  const float* W_hh  = (const float*)d_in[2];
  const float* b_ih  = (const float*)d_in[3];
  const float* b_hh  = (const float*)d_in[4];
  const float* W_lin = (const float*)d_in[5];
  const float* b_lin = (const float*)d_in[6];

  char* ws = (char*)d_ws;
  size_t off = 0;
  auto alloc = [&](size_t bytes) { void* p = ws + off; off += (bytes + 255) & ~(size_t)255; return p; };
  f16*      Wih16  = (f16*)alloc((size_t)GATES * LSTM_H * 2);
  f16*      Wlin16 = (f16*)alloc((size_t)LSTM_O * LSTM_H * 2);
  f16*      C16    = (f16*)alloc((size_t)LSTM_B * LSTM_H * 2);
  f16*      Wpack  = (f16*)alloc((size_t)GATES * LSTM_H * 2);
  float*    xp     = (float*)alloc((size_t)LSTM_B * GATES * 4);
  f16*      hist   = (f16*)alloc((size_t)LSTM_T * LSTM_B * LSTM_H * 2);
  unsigned* ready  = (unsigned*)alloc((size_t)LSTM_T * 1024 * 4);   // [t][mb][kc] 64B-spaced

  cvt4_kernel<<<2048, 256, 0, stream>>>((const float4*)W_ih,  (f16x4*)Wih16,  GATES * LSTM_H / 4);
  cvt4_kernel<<<512,  256, 0, stream>>>((const float4*)W_lin, (f16x4*)Wlin16, LSTM_O * LSTM_H / 4);
  cvt4_kernel<<<256,  256, 0, stream>>>((const float4*)C,     (f16x4*)C16,    LSTM_B * LSTM_H / 4);
  pack_whh_kernel<<<2048, 256, 0, stream>>>(W_hh, Wpack);
  hipMemsetAsync(ready, 0, (size_t)LSTM_T * 1024 * 4, stream);

  // x_proj = C @ W_ih^T + b_ih + b_hh (input constant across time)
  gemm_bt_kernel<<<(LSTM_B / 64) * (GATES / 64), 256, 0, stream>>>(
      C16, Wih16, b_ih, b_hh, xp, LSTM_B, GATES, LSTM_H, GATES / 64, 0, 0);

  // recurrence: one cooperative kernel, all 128 steps, dataflow-synced
  {
    const f16* wp = Wpack; const float* xpp = xp; f16* hp = hist; unsigned* rp = ready;
    void* args[] = { (void*)&wp, (void*)&xpp, (void*)&hp, (void*)&rp };
    hipLaunchCooperativeKernel((void*)lstm_persist_kernel, dim3(256), dim3(256), args, 0, stream);
  }

  // ys = hist @ W_lin^T + b_lin, one batched GEMM over blocked hist
  gemm_bt_kernel<<<(LSTM_T * LSTM_B / 64) * (LSTM_O / 64), 256, 0, stream>>>(
      hist, Wlin16, b_lin, nullptr, (float*)d_out,
      LSTM_T * LSTM_B, LSTM_O, LSTM_H, LSTM_O / 64, 1, 1);
}

// Round 13
// 930.561 us; speedup vs baseline: 1.3742x; 1.3742x over previous
//
#include <hip/hip_runtime.h>

typedef _Float16 f16;
typedef _Float16 f16x4 __attribute__((ext_vector_type(4)));
typedef _Float16 f16x8 __attribute__((ext_vector_type(8)));
typedef float f32x2 __attribute__((ext_vector_type(2)));
typedef float f32x4 __attribute__((ext_vector_type(4)));

#define LSTM_B 256
#define LSTM_H 1024
#define LSTM_O 512
#define LSTM_T 128
#define GATES 4096

// hist blocked layout: element (t, b, h) at
//   ((t*64 + (h>>4))*4 + (b>>6))*1024 + (b&63)*16 + (h&15)
// -> producer WG writes ONE contiguous 2KB block per step, and consumer MFMA
//    A-fragments are directly loadable: a wave's lanes 0-31 cover one
//    contiguous 512B span, lanes 32-63 the next block's span (coalesced).

// ---------------- fp32 -> fp16 convert (vectorized) ----------------
__global__ void cvt4_kernel(const float4* __restrict__ src, f16x4* __restrict__ dst, int n4) {
  int i = blockIdx.x * blockDim.x + threadIdx.x;
  int st = gridDim.x * blockDim.x;
  for (; i < n4; i += st) {
    float4 v = src[i];
    f16x4 o; o[0] = (f16)v.x; o[1] = (f16)v.y; o[2] = (f16)v.z; o[3] = (f16)v.w;
    dst[i] = o;
  }
}

// ---------------- pack Whh into fragment-linear f16 layout ----------------
__global__ void pack_whh_kernel(const float* __restrict__ Whh, f16* __restrict__ Wpack) {
  int idx = blockIdx.x * 256 + threadIdx.x;      // 64*128*64 = 524288 threads
  int lane = idx & 63;
  int f = (idx >> 6) & 127;
  int hj = idx >> 13;
  int kc = f >> 3, s = (f >> 2) & 1, wn = (f >> 1) & 1, nt = f & 1;
  int c = wn * 32 + nt * 16 + (lane & 15);
  int row = (c >> 4) * 1024 + hj * 16 + (c & 15);
  int k0 = kc * 64 + s * 32 + (lane >> 4) * 8;
  const float* src = Whh + (size_t)row * LSTM_H + k0;
  float4 v0 = *(const float4*)src;
  float4 v1 = *(const float4*)(src + 4);
  f16x8 o;
  o[0] = (f16)v0.x; o[1] = (f16)v0.y; o[2] = (f16)v0.z; o[3] = (f16)v0.w;
  o[4] = (f16)v1.x; o[5] = (f16)v1.y; o[6] = (f16)v1.z; o[7] = (f16)v1.w;
  *(f16x8*)(Wpack + (size_t)idx * 8) = o;
}

// ---------------- generic C[M,N] = A[MxK] * Bw[NxK]^T + bias ----------------
__global__ __launch_bounds__(256) void gemm_bt_kernel(
    const f16* __restrict__ A, const f16* __restrict__ Bw,
    const float* __restrict__ bias0, const float* __restrict__ bias1,
    float* __restrict__ out, int M, int N, int K, int gn, int xswz, int blkA)
{
  __shared__ __align__(16) f16 As[64][72];
  __shared__ __align__(16) f16 Bs[64][72];
  int bx = blockIdx.x;
  if (xswz) { int n = gridDim.x; bx = (bx & 7) * (n >> 3) + (bx >> 3); }  // bijective: n%8==0
  int mb = bx / gn;
  int m0 = mb * 64;
  int n0 = (bx - mb * gn) * 64;
  int tid = threadIdx.x;
  int lane = tid & 63, w = tid >> 6;
  int wm = w >> 1, wn = w & 1;
  int sr = tid >> 2, sseg = tid & 3;
  const f16* ga;
  size_t kadv;
  if (blkA) {
    int m = m0 + sr;
    ga = A + ((size_t)(m >> 8) * 256 + (size_t)sseg * 4 + ((m >> 6) & 3)) * 1024 + (m & 63) * 16;
    kadv = 16384;
  } else {
    ga = A + (size_t)(m0 + sr) * K + sseg * 16;
    kadv = 64;
  }
  const f16* gb = Bw + (size_t)(n0 + sr) * K + sseg * 16;
  f32x4 acc00 = {}, acc01 = {}, acc10 = {}, acc11 = {};
  f16x8 ra0 = *(const f16x8*)ga, ra1 = *(const f16x8*)(ga + 8);
  f16x8 rb0 = *(const f16x8*)gb, rb1 = *(const f16x8*)(gb + 8);
  for (int kc = 0; kc < K; kc += 64) {
    __syncthreads();
    *(f16x8*)&As[sr][sseg * 16]     = ra0;
    *(f16x8*)&As[sr][sseg * 16 + 8] = ra1;
    *(f16x8*)&Bs[sr][sseg * 16]     = rb0;
    *(f16x8*)&Bs[sr][sseg * 16 + 8] = rb1;
    __syncthreads();
    if (kc + 64 < K) {
      ga += kadv; gb += 64;
      ra0 = *(const f16x8*)ga; ra1 = *(const f16x8*)(ga + 8);
      rb0 = *(const f16x8*)gb; rb1 = *(const f16x8*)(gb + 8);
    }
    int g = lane >> 4, r = lane & 15;
    #pragma unroll
    for (int s = 0; s < 2; s++) {
      f16x8 a0 = *(const f16x8*)&As[wm * 32      + r][s * 32 + g * 8];
      f16x8 a1 = *(const f16x8*)&As[wm * 32 + 16 + r][s * 32 + g * 8];
      f16x8 b0 = *(const f16x8*)&Bs[wn * 32      + r][s * 32 + g * 8];
      f16x8 b1 = *(const f16x8*)&Bs[wn * 32 + 16 + r][s * 32 + g * 8];
      acc00 = __builtin_amdgcn_mfma_f32_16x16x32_f16(a0, b0, acc00, 0, 0, 0);
      acc01 = __builtin_amdgcn_mfma_f32_16x16x32_f16(a0, b1, acc01, 0, 0, 0);
      acc10 = __builtin_amdgcn_mfma_f32_16x16x32_f16(a1, b0, acc10, 0, 0, 0);
      acc11 = __builtin_amdgcn_mfma_f32_16x16x32_f16(a1, b1, acc11, 0, 0, 0);
    }
  }
  int gq = lane >> 4, rr = lane & 15;
  f32x4 accs[2][2] = {{acc00, acc01}, {acc10, acc11}};
  #pragma unroll
  for (int mt = 0; mt < 2; mt++)
    #pragma unroll
    for (int nt = 0; nt < 2; nt++) {
      int row = m0 + wm * 32 + mt * 16 + gq * 4;
      int col = n0 + wn * 32 + nt * 16 + rr;
      float bv = bias0 ? bias0[col] : 0.f;
      if (bias1) bv += bias1[col];
      #pragma unroll
      for (int j = 0; j < 4; j++)
        out[(size_t)(row + j) * N + col] = accs[mt][nt][j] + bv;
    }
}

// ---------------- persistent LSTM recurrence (dataflow-synced) ----------------
// ready[((t*4+mb)*16+kc)*16]: producers (hj = 4kc..4kc+3) each add 1 after their
// h-block store has drained to LLC (sc0 sc1 + vmcnt(0)). Consumers poll ==4 with
// relaxed agent loads (LLC-coherent), then load A-fragments straight from global.
// No group barrier, no fences, no LDS staging for A, no syncthreads in K-loop.
__device__ __forceinline__ void wait_chunk(const unsigned* p) {
  while (__hip_atomic_load(p, __ATOMIC_RELAXED, __HIP_MEMORY_SCOPE_AGENT) < 4u)
    __builtin_amdgcn_s_sleep(2);
  asm volatile("" ::: "memory");   // block hoisting of A-loads above the flag
}

__global__ __launch_bounds__(256, 1) void lstm_persist_kernel(
    const f16* __restrict__ Wpack, const float* __restrict__ xp,
    f16* __restrict__ hist, unsigned* __restrict__ ready)
{
  __shared__ __align__(16) f16 Bres[65536];      // 128 KB resident Whh frags
  __shared__ float gsm[64][65];                  // gate exchange

  const int wg = blockIdx.x;
  const int mb = (wg & 7) >> 1;                        // XCD pair -> batch group
  const int hj = ((wg >> 3) << 1) | (wg & 1);          // 64 hid-slices per group
  const int m0 = mb * 64;
  const int tid = threadIdx.x;
  const int lane = tid & 63, w = tid >> 6;
  const int wm = w >> 1, wn = w & 1;
  const int g = lane >> 4, r = lane & 15;

  // one-time: Whh fragment strip -> LDS
  {
    const f16x8* src = (const f16x8*)(Wpack + (size_t)hj * 65536);
    f16x8* dst = (f16x8*)Bres;
    for (int i = tid; i < 8192; i += 256) dst[i] = src[i];
  }

  // one-time: per-thread x_proj and c registers
  const int b_loc = tid & 63, hh0 = tid >> 6;
  const float* xprow = xp + (size_t)(m0 + b_loc) * GATES + hj * 16 + hh0 * 4;
  float4 xi = *(const float4*)(xprow);
  float4 xf = *(const float4*)(xprow + LSTM_H);
  float4 xg = *(const float4*)(xprow + 2 * LSTM_H);
  float4 xo = *(const float4*)(xprow + 3 * LSTM_H);
  float xiv[4] = {xi.x, xi.y, xi.z, xi.w};
  float xfv[4] = {xf.x, xf.y, xf.z, xf.w};
  float xgv[4] = {xg.x, xg.y, xg.z, xg.w};
  float xov[4] = {xo.x, xo.y, xo.z, xo.w};
  float cvv[4] = {0.f, 0.f, 0.f, 0.f};

  // A-fragment invariant offset (f16 units) within a timestep slab:
  //   addr = t*262144 + kc*16384 + s*8192 + mt*256 + inv
  const int inv = (g >> 1) * 4096 + mb * 1024 + wm * 512 + r * 16 + (g & 1) * 8;
  const int stag = hj >> 2;                            // start at own chunk
  const int bbo = wn * 2048 + lane * 16;               // B frag byte offset base
  f16* hob = hist + ((size_t)hj * 4 + mb) * 1024 + b_loc * 16 + hh0 * 4;
  unsigned* myflag = ready + (size_t)mb * 256 + (size_t)(hj >> 2) * 16;

  __syncthreads();   // Bres ready

  for (int t = 0; t < LSTM_T; t++) {
    f32x4 acc00 = {}, acc01 = {}, acc10 = {}, acc11 = {};
    if (t > 0) {
      const f16* hb = hist + (size_t)(t - 1) * 262144 + inv;
      const unsigned* rdt = ready + (size_t)(t - 1) * 1024 + (size_t)mb * 256;
      f16x8 sA[3][4];
      // 3-stage prologue
      #pragma unroll
      for (int j = 0; j < 3; j++) {
        const int kc = (stag + j) & 15;
        wait_chunk(rdt + kc * 16);
        const f16* p = hb + kc * 16384;
        sA[j][0] = *(const f16x8*)(p);
        sA[j][1] = *(const f16x8*)(p + 256);
        sA[j][2] = *(const f16x8*)(p + 8192);
        sA[j][3] = *(const f16x8*)(p + 8448);
      }
      #pragma unroll
      for (int i = 0; i < 16; i++) {
        const int kc = (stag + i) & 15;
        const int st = i % 3;
        const char* Bb = (const char*)Bres + kc * 8192;
        f16x8 b00 = *(const f16x8*)(Bb + bbo);
        f16x8 b10 = *(const f16x8*)(Bb + bbo + 1024);
        f16x8 b01 = *(const f16x8*)(Bb + 4096 + bbo);
        f16x8 b11 = *(const f16x8*)(Bb + 4096 + bbo + 1024);
        acc00 = __builtin_amdgcn_mfma_f32_16x16x32_f16(sA[st][0], b00, acc00, 0, 0, 0);
        acc01 = __builtin_amdgcn_mfma_f32_16x16x32_f16(sA[st][0], b10, acc01, 0, 0, 0);
        acc10 = __builtin_amdgcn_mfma_f32_16x16x32_f16(sA[st][1], b00, acc10, 0, 0, 0);
        acc11 = __builtin_amdgcn_mfma_f32_16x16x32_f16(sA[st][1], b10, acc11, 0, 0, 0);
        acc00 = __builtin_amdgcn_mfma_f32_16x16x32_f16(sA[st][2], b01, acc00, 0, 0, 0);
        acc01 = __builtin_amdgcn_mfma_f32_16x16x32_f16(sA[st][2], b11, acc01, 0, 0, 0);
        acc10 = __builtin_amdgcn_mfma_f32_16x16x32_f16(sA[st][3], b01, acc10, 0, 0, 0);
        acc11 = __builtin_amdgcn_mfma_f32_16x16x32_f16(sA[st][3], b11, acc11, 0, 0, 0);
        if (i + 3 < 16) {                       // refill stage with chunk i+3
          const int kn = (stag + i + 3) & 15;
          wait_chunk(rdt + kn * 16);
          const f16* p = hb + kn * 16384;
          sA[st][0] = *(const f16x8*)(p);
          sA[st][1] = *(const f16x8*)(p + 256);
          sA[st][2] = *(const f16x8*)(p + 8192);
          sA[st][3] = *(const f16x8*)(p + 8448);
        }
      }
    }
    // gates tile -> gsm
    {
      f32x4 accs[2][2] = {{acc00, acc01}, {acc10, acc11}};
      #pragma unroll
      for (int mt = 0; mt < 2; mt++)
        #pragma unroll
        for (int nt = 0; nt < 2; nt++)
          #pragma unroll
          for (int j = 0; j < 4; j++)
            gsm[wm * 32 + mt * 16 + g * 4 + j][wn * 32 + nt * 16 + r] = accs[mt][nt][j];
    }
    __syncthreads();
    // elementwise cell update (c and x_proj in registers)
    float hnew[4];
    #pragma unroll
    for (int u = 0; u < 4; u++) {
      int hh = hh0 * 4 + u;
      float iv = gsm[b_loc][hh]      + xiv[u];
      float fv = gsm[b_loc][16 + hh] + xfv[u];
      float gv = gsm[b_loc][32 + hh] + xgv[u];
      float ov = gsm[b_loc][48 + hh] + xov[u];
      iv = 1.f / (1.f + __expf(-iv));
      fv = 1.f / (1.f + __expf(-fv));
      gv = 2.f / (1.f + __expf(-2.f * gv)) - 1.f;
      ov = 1.f / (1.f + __expf(-ov));
      float cn = fv * cvv[u] + iv * gv;
      cvv[u] = cn;
      float tc = 2.f / (1.f + __expf(-2.f * cn)) - 1.f;
      hnew[u] = ov * tc;
    }
    f16x4 hw; hw[0] = (f16)hnew[0]; hw[1] = (f16)hnew[1]; hw[2] = (f16)hnew[2]; hw[3] = (f16)hnew[3];
    // write-through store (sc0 sc1): coherent at LLC, no dirty L2 line
    {
      union { f16x4 h; f32x2 f2; } hu; hu.h = hw;
      f16* haddr = hob + (size_t)t * 262144;
      asm volatile("global_store_dwordx2 %0, %1, off sc0 sc1" :: "v"(haddr), "v"(hu.f2) : "memory");
    }
    asm volatile("s_waitcnt vmcnt(0)" ::: "memory");   // this wave's h-store at LLC
    __syncthreads();                                   // all waves drained (+ gsm reads done)
    if (tid == 0)
      __hip_atomic_fetch_add(myflag + (size_t)t * 1024, 1u,
                             __ATOMIC_RELAXED, __HIP_MEMORY_SCOPE_AGENT);
  }
}

extern "C" void kernel_launch(void* const* d_in, const int* in_sizes, int n_in,
                              void* d_out, int out_size, void* d_ws, size_t ws_size,
                              hipStream_t stream)
{
  (void)in_sizes; (void)n_in; (void)out_size; (void)ws_size;
  const float* C     = (const float*)d_in[0];
  const float* W_ih  = (const float*)d_in[1];
  const float* W_hh  = (const float*)d_in[2];
  const float* b_ih  = (const float*)d_in[3];
  const float* b_hh  = (const float*)d_in[4];
  const float* W_lin = (const float*)d_in[5];
  const float* b_lin = (const float*)d_in[6];

  char* ws = (char*)d_ws;
  size_t off = 0;
  auto alloc = [&](size_t bytes) { void* p = ws + off; off += (bytes + 255) & ~(size_t)255; return p; };
  f16*      Wih16  = (f16*)alloc((size_t)GATES * LSTM_H * 2);
  f16*      Wlin16 = (f16*)alloc((size_t)LSTM_O * LSTM_H * 2);
  f16*      C16    = (f16*)alloc((size_t)LSTM_B * LSTM_H * 2);
  f16*      Wpack  = (f16*)alloc((size_t)GATES * LSTM_H * 2);
  float*    xp     = (float*)alloc((size_t)LSTM_B * GATES * 4);
  f16*      hist   = (f16*)alloc((size_t)LSTM_T * LSTM_B * LSTM_H * 2);
  unsigned* ready  = (unsigned*)alloc((size_t)LSTM_T * 1024 * 4);   // [t][mb][kc] 64B-spaced

  cvt4_kernel<<<2048, 256, 0, stream>>>((const float4*)W_ih,  (f16x4*)Wih16,  GATES * LSTM_H / 4);
  cvt4_kernel<<<512,  256, 0, stream>>>((const float4*)W_lin, (f16x4*)Wlin16, LSTM_O * LSTM_H / 4);
  cvt4_kernel<<<256,  256, 0, stream>>>((const float4*)C,     (f16x4*)C16,    LSTM_B * LSTM_H / 4);
  pack_whh_kernel<<<2048, 256, 0, stream>>>(W_hh, Wpack);
  hipMemsetAsync(ready, 0, (size_t)LSTM_T * 1024 * 4, stream);

  // x_proj = C @ W_ih^T + b_ih + b_hh (input constant across time)
  gemm_bt_kernel<<<(LSTM_B / 64) * (GATES / 64), 256, 0, stream>>>(
      C16, Wih16, b_ih, b_hh, xp, LSTM_B, GATES, LSTM_H, GATES / 64, 0, 0);

  // recurrence: one cooperative kernel, all 128 steps, dataflow-synced
  {
    const f16* wp = Wpack; const float* xpp = xp; f16* hp = hist; unsigned* rp = ready;
    void* args[] = { (void*)&wp, (void*)&xpp, (void*)&hp, (void*)&rp };
    hipLaunchCooperativeKernel((void*)lstm_persist_kernel, dim3(256), dim3(256), args, 0, stream);
  }

  // ys = hist @ W_lin^T + b_lin, one batched GEMM over blocked hist
  gemm_bt_kernel<<<(LSTM_T * LSTM_B / 64) * (LSTM_O / 64), 256, 0, stream>>>(
      hist, Wlin16, b_lin, nullptr, (float*)d_out,
      LSTM_T * LSTM_B, LSTM_O, LSTM_H, LSTM_O / 64, 1, 1);
}